// Round 9
// baseline (217.000 us; speedup 1.0000x reference)
//
#include <hip/hip_runtime.h>
#include <hip/hip_bf16.h>

static constexpr int NN = 768;

typedef short v8bf __attribute__((ext_vector_type(8)));   // 8 bf16 (4 VGPRs)
typedef float v4f  __attribute__((ext_vector_type(4)));

__device__ __forceinline__ unsigned short f2bf(float f) {
  unsigned u = __float_as_uint(f);
  u += 0x7fffu + ((u >> 16) & 1u);          // RNE
  return (unsigned short)(u >> 16);
}
__device__ __forceinline__ float bf2f(unsigned short s) {
  return __uint_as_float(((unsigned)s) << 16);
}

// -------- workspace layout (float units; all multiples of 64) --------
static constexpr size_t OFF_ISA    = 0;          // 1024 ints
static constexpr size_t OFF_WCT    = 1024;       // 48x128 bf16
static constexpr size_t OFF_BCAT   = 4096;       // 48 f32
static constexpr size_t OFF_SBF    = 4160;       // 768x384 bf16
static constexpr size_t OFF_WQT    = 151616;     // 768x384 bf16
static constexpr size_t OFF_WKVT   = 299072;     // 1536x384 bf16
static constexpr size_t OFF_WQPT   = 593984;     // 192x384 bf16 (144 used)
static constexpr size_t OFF_WKVPT  = 630848;     // 448x384 bf16 (432 used)
static constexpr size_t OFF_TFNQT  = 716864;     // 768x256 bf16 (K=192 + zero pad)
static constexpr size_t OFF_TFNKVT = 815168;     // 1536x256 bf16
static constexpr size_t OFF_WOUTT  = 1011776;    // 384x1536 bf16
static constexpr size_t OFF_TFNOT  = 1306688;    // 192x1280 bf16 (K=1248 + zero pad)
static constexpr size_t OFF_QR     = 1429568;    // 768x768 bf16
static constexpr size_t OFF_KVR    = 1724480;    // 768x1536 bf16
static constexpr size_t OFF_QP     = 2314304;    // 768x144 f32
static constexpr size_t OFF_KVP    = 2424896;    // 768x432 f32
static constexpr size_t OFF_QA     = 2756672;    // 768x768 bf16
static constexpr size_t OFF_KVA    = 3051584;    // 768x1536 bf16
static constexpr size_t OFF_QCAT   = 3641408;    // 768x12x96 bf16
static constexpr size_t OFF_KCAT   = 4083776;    // 768x12x96 bf16
static constexpr size_t OFF_RQ     = 4526144;    // 12x768 f32
static constexpr size_t OFF_RK     = 4535360;    // 12x768 f32
static constexpr size_t OFF_VCATT  = 4986944;    // 12x96x768 bf16
static constexpr size_t OFF_BB     = 5429312;    // 12x768x768 bf16 ([h][n][m])
static constexpr size_t OFF_PZT    = 8968256;    // 768x32x768 bf16
static constexpr size_t OFF_ABF    = 18405440;   // 12x768x768 bf16 ([h][n][m])
static constexpr size_t OFF_OPTRAW = 21944384;   // 768x288 f32
static constexpr size_t OFF_RESF   = 22165568;   // 768x1536 bf16
static constexpr size_t OFF_ATOMF  = 22755392;   // 768x1280 bf16 (1248 used)

// ================= prep0: detect + wcat + all weight converts =================
__device__ void transpose_cv(const float* __restrict__ src, unsigned short* __restrict__ dst,
                             int K, int Kp, int N, int ky, int nx) {
  __shared__ float tl[32][33];
  const int k0 = ky * 32, n0 = nx * 32;
  const int tx = threadIdx.x & 31, ty = threadIdx.x >> 5;
  for (int it = 0; it < 4; ++it) {
    int r = ty + it * 8;
    float v = 0.f;
    if (k0 + r < K && n0 + tx < N) v = src[(long long)(k0 + r) * N + n0 + tx];
    tl[r][tx] = v;
  }
  __syncthreads();
  for (int it = 0; it < 4; ++it) {
    int r = ty + it * 8;
    if (n0 + r < N && k0 + tx < Kp)
      dst[(long long)(n0 + r) * Kp + k0 + tx] = f2bf(tl[tx][r]);
  }
}

__global__ __launch_bounds__(256) void prep0(
    float* wsf, const float* s, const float* wq, const float* wkv,
    const float* wqp, const float* wkvp, const float* tfnq_ws,
    const float* tfnkv_ws, const float* wout, const float* tfno_ws,
    const float* wb, const float* wdz, const float* bb, const float* bdz,
    const unsigned int* isa_raw)
{
  const int bx = blockIdx.x, t = threadIdx.x;
  if (bx < 288)       { int g = bx;        transpose_cv(wq,      (unsigned short*)(wsf+OFF_WQT),    384, 384, 768,  g/24, g%24); return; }
  else if (bx < 864)  { int g = bx-288;    transpose_cv(wkv,     (unsigned short*)(wsf+OFF_WKVT),   384, 384, 1536, g/48, g%48); return; }
  else if (bx < 924)  { int g = bx-864;    transpose_cv(wqp,     (unsigned short*)(wsf+OFF_WQPT),   384, 384, 144,  g/5,  g%5);  return; }
  else if (bx < 1092) { int g = bx-924;    transpose_cv(wkvp,    (unsigned short*)(wsf+OFF_WKVPT),  384, 384, 432,  g/14, g%14); return; }
  else if (bx < 1284) { int g = bx-1092;   transpose_cv(tfnq_ws, (unsigned short*)(wsf+OFF_TFNQT),  192, 256, 768,  g/24, g%24); return; }
  else if (bx < 1668) { int g = bx-1284;   transpose_cv(tfnkv_ws,(unsigned short*)(wsf+OFF_TFNKVT), 192, 256, 1536, g/48, g%48); return; }
  else if (bx < 2244) { int g = bx-1668;   transpose_cv(wout,    (unsigned short*)(wsf+OFF_WOUTT),  1536,1536,384,  g/12, g%12); return; }
  else if (bx < 2484) { int g = bx-2244;   transpose_cv(tfno_ws, (unsigned short*)(wsf+OFF_TFNOT),  1248,1280,192,  g/6,  g%6);  return; }
  else if (bx < 2772) {
    long long base = (long long)(bx - 2484) * 1024 + t * 4;
    float4 v = *(const float4*)(s + base);
    unsigned short tmp[4] = {f2bf(v.x), f2bf(v.y), f2bf(v.z), f2bf(v.w)};
    *(uint2*)((unsigned short*)(wsf + OFF_SBF) + base) = *(uint2*)tmp;
    return;
  } else if (bx < 2773) {
    __shared__ int notint, notfloat;
    int* ISA = (int*)wsf;
    if (t == 0) { notint = 0; notfloat = 0; }
    __syncthreads();
    if (t < 192) {
      unsigned v = isa_raw[t];
      if (v > 1u) atomicOr(&notint, 1);
      if (v != 0u && v != 0x3F800000u) atomicOr(&notfloat, 1);
    }
    __syncthreads();
    const int mode = (!notint) ? 0 : ((!notfloat) ? 1 : 2);
    for (int n = t; n < NN; n += 256) {
      int val;
      if (mode == 2) val = (((const unsigned char*)isa_raw)[n] != 0);
      else           val = (isa_raw[n] != 0u);
      ISA[n] = val;
    }
    return;
  } else {
    const float rs3 = 0.57735026918962576f;
    unsigned short* WCT = (unsigned short*)(wsf + OFF_WCT);
    float* bcat = wsf + OFF_BCAT;
    int idx = (bx - 2773) * 256 + t;
    if (idx < 48 * 128) {
      int o = idx >> 7, k = idx & 127;
      float v = 0.f;
      if (o < 12) v = rs3 * wb[k * 12 + o];
      else if (o < 44) v = wdz[k * 32 + (o - 12)];
      WCT[o * 128 + k] = f2bf(v);
    }
    if (bx == 2773 && t < 48)
      bcat[t] = (t < 12) ? rs3 * bb[t] : (t < 44 ? bdz[t - 12] : 0.f);
  }
}

// ================= gemm16: 16 rows x 64 cols, 4-wave split-K =================
__device__ __forceinline__ void gemm16(
    char* lds, const unsigned short* __restrict__ A, int lda,
    const unsigned short* __restrict__ BT, int ldb, int KQ,
    const float* __restrict__ bias, int mode,
    float* Cf, unsigned short* Cb, int ldc, int Nc, int colb, int row0,
    const int* __restrict__ ISA, float* outp)
{
  v4f (*PS)[4][64] = (v4f (*)[4][64])lds;
  const int t = threadIdx.x, w = t >> 6, l = t & 63, l15 = l & 15, lg = l >> 4;
  const int rowA = row0 + l15;
  v4f acc[4] = {};
  const unsigned short* ap = A + (long long)rowA * lda + lg * 8;
  const int kend = (w + 1) * KQ;
  for (int k0 = w * KQ; k0 < kend; k0 += 32) {
    v8bf av = *(const v8bf*)(ap + k0);
#pragma unroll
    for (int cf = 0; cf < 4; ++cf) {
      v8bf bv = *(const v8bf*)(BT + (long long)(colb + cf * 16 + l15) * ldb + k0 + lg * 8);
      acc[cf] = __builtin_amdgcn_mfma_f32_16x16x32_bf16(av, bv, acc[cf], 0, 0, 0);
    }
  }
#pragma unroll
  for (int cf = 0; cf < 4; ++cf) PS[w][cf][l] = acc[cf];
  __syncthreads();
  const int cf = w;
  v4f sv = PS[0][cf][l] + PS[1][cf][l] + PS[2][cf][l] + PS[3][cf][l];
  const int c = colb + cf * 16 + l15;
  if (c < Nc) {
    float bvs = bias ? bias[c] : 0.f;
#pragma unroll
    for (int i = 0; i < 4; ++i) {
      int r = row0 + lg * 4 + i;
      float v = sv[i] + bvs;
      if (mode == 0)      Cf[(long long)r * ldc + c] = v;
      else if (mode == 1) Cb[(long long)r * ldc + c] = f2bf(v);
      else if (mode == 2) { if (!ISA[r]) outp[r * 384 + c] = v; }
      else                { if ( ISA[r]) outp[r * 384 + c] = v; }
    }
  }
}

// ================= mega1: zpass direct-reg (4608) || projection GEMMs (3936) =========
__global__ __launch_bounds__(256) void mega1(
    float* wsf, const float* __restrict__ z,
    const float* bq, const float* bkv, const float* bqp, const float* bkvp)
{
  __shared__ __align__(16) char lds[23296];
  const int t = threadIdx.x;
  if (blockIdx.x < 4608) {
    float* Sout = (float*)lds;
    const unsigned short* WCT = (const unsigned short*)(wsf + OFF_WCT);
    const float* bcat = wsf + OFF_BCAT;
    unsigned short* Bb  = (unsigned short*)(wsf + OFF_BB);
    unsigned short* PZT = (unsigned short*)(wsf + OFF_PZT);
    const long long row0 = (long long)blockIdx.x * 128;
    const int w = t >> 6, l = t & 63, l15 = l & 15, lg = l >> 4;
    v8bf bvv[4][3];
#pragma unroll
    for (int ks = 0; ks < 4; ++ks)
#pragma unroll
      for (int cf = 0; cf < 3; ++cf)
        bvv[ks][cf] = *(const v8bf*)(WCT + (cf * 16 + l15) * 128 + ks * 32 + lg * 8);
    v4f acc[2][3] = {};
#pragma unroll
    for (int rf = 0; rf < 2; ++rf) {
      const float* zrow = z + (row0 + w * 32 + rf * 16 + l15) * 128 + lg * 8;
#pragma unroll
      for (int ks = 0; ks < 4; ++ks) {
        float4 a0 = *(const float4*)(zrow + ks * 32);
        float4 a1 = *(const float4*)(zrow + ks * 32 + 4);
        unsigned short tmp[8] = {f2bf(a0.x), f2bf(a0.y), f2bf(a0.z), f2bf(a0.w),
                                 f2bf(a1.x), f2bf(a1.y), f2bf(a1.z), f2bf(a1.w)};
        v8bf av = *(const v8bf*)tmp;
#pragma unroll
        for (int cf = 0; cf < 3; ++cf)
          acc[rf][cf] = __builtin_amdgcn_mfma_f32_16x16x32_bf16(av, bvv[ks][cf], acc[rf][cf], 0, 0, 0);
      }
    }
#pragma unroll
    for (int rf = 0; rf < 2; ++rf)
#pragma unroll
      for (int cf = 0; cf < 3; ++cf) {
        int o = cf * 16 + l15;
#pragma unroll
        for (int i = 0; i < 4; ++i) {
          int m = w * 32 + rf * 16 + lg * 4 + i;
          Sout[o * 132 + m] = acc[rf][cf][i];
        }
      }
    __syncthreads();
    const int n = blockIdx.x / 6;
    const int m0 = (blockIdx.x % 6) * 128;
    for (int idx = t; idx < 44 * 8; idx += 256) {
      int o = idx >> 3, seg = idx & 7;
      float bias = bcat[o];
      unsigned short tmp[16];
#pragma unroll
      for (int j = 0; j < 16; ++j) tmp[j] = f2bf(Sout[o * 132 + seg * 16 + j] + bias);
      unsigned short* gp;
      if (o < 12) gp = Bb + ((long long)o * 768 + n) * 768 + m0 + seg * 16;
      else        gp = PZT + ((long long)n * 32 + (o - 12)) * 768 + m0 + seg * 16;
      *(uint4*)gp = *(uint4*)tmp;
      *(uint4*)(gp + 8) = *(uint4*)(tmp + 8);
    }
    return;
  }
  // ---- projection GEMMs ----
  const int g = blockIdx.x - 4608;
  const int bt = g / 82, xt = g % 82;
  const unsigned short* SBF = (const unsigned short*)(wsf + OFF_SBF);
  const unsigned short* BT; const float* bias; int ldb, KQ, mode, ldc, Nc, colb;
  float* Cf = nullptr; unsigned short* Cb = nullptr;
  if (xt < 12)      { BT=(const unsigned short*)(wsf+OFF_WQT);    bias=bq;     ldb=384; KQ=96; Cb=(unsigned short*)(wsf+OFF_QR);  ldc=768;  Nc=768;  colb=xt*64;      mode=1; }
  else if (xt < 36) { BT=(const unsigned short*)(wsf+OFF_WKVT);   bias=bkv;    ldb=384; KQ=96; Cb=(unsigned short*)(wsf+OFF_KVR); ldc=1536; Nc=1536; colb=(xt-12)*64; mode=1; }
  else if (xt < 39) { BT=(const unsigned short*)(wsf+OFF_WQPT);   bias=bqp;    ldb=384; KQ=96; Cf=wsf+OFF_QP;                     ldc=144;  Nc=144;  colb=(xt-36)*64; mode=0; }
  else if (xt < 46) { BT=(const unsigned short*)(wsf+OFF_WKVPT);  bias=bkvp;   ldb=384; KQ=96; Cf=wsf+OFF_KVP;                    ldc=432;  Nc=432;  colb=(xt-39)*64; mode=0; }
  else if (xt < 58) { BT=(const unsigned short*)(wsf+OFF_TFNQT);  bias=nullptr;ldb=256; KQ=64; Cb=(unsigned short*)(wsf+OFF_QA);  ldc=768;  Nc=768;  colb=(xt-46)*64; mode=1; }
  else              { BT=(const unsigned short*)(wsf+OFF_TFNKVT); bias=nullptr;ldb=256; KQ=64; Cb=(unsigned short*)(wsf+OFF_KVA); ldc=1536; Nc=1536; colb=(xt-58)*64; mode=1; }
  gemm16(lds, SBF, 384, BT, ldb, KQ, bias, mode, Cf, Cb, ldc, Nc, colb, bt * 16, nullptr, nullptr);
}

// ================= prep_qkv (writes VcatT transposed directly) =================
__global__ __launch_bounds__(256) void prep_qkv(
    float* wsf, const float* __restrict__ s,
    const float* __restrict__ rot, const float* __restrict__ trans,
    const float* __restrict__ head_w,
    const float* __restrict__ tfnq_wv, const float* __restrict__ tfnkv_wv)
{
  const int n = blockIdx.x, t = threadIdx.x;
  const int* ISA = (const int*)wsf;
  const unsigned short* QRb  = (const unsigned short*)(wsf + OFF_QR);
  const unsigned short* KVRb = (const unsigned short*)(wsf + OFF_KVR);
  const unsigned short* QAb  = (const unsigned short*)(wsf + OFF_QA);
  const unsigned short* KVAb = (const unsigned short*)(wsf + OFF_KVA);
  const float* QP  = wsf + OFF_QP;
  const float* KVP = wsf + OFF_KVP;
  unsigned short* Qcat = (unsigned short*)(wsf + OFF_QCAT);
  unsigned short* Kcat = (unsigned short*)(wsf + OFF_KCAT);
  unsigned short* Vt   = (unsigned short*)(wsf + OFF_VCATT);
  float* rq = wsf + OFF_RQ;
  float* rk = wsf + OFF_RK;
  const bool isa = ISA[n] != 0;
  __shared__ float R[9], T[3], shw[12], sv[192];
  __shared__ float qs[768], ks[768], vs[768], qp[144], kp[144], vp[288];
  if (t < 9) R[t] = rot[n * 9 + t];
  if (t < 3) T[t] = trans[n * 3 + t];
  if (t >= 16 && t < 28)
    shw[t - 16] = log1pf(__expf(head_w[t - 16])) * 0.13608276348795434f;
  if (isa && t >= 32 && t < 224) sv[t - 32] = s[(size_t)n * 384 + 192 + (t - 32)];
  __syncthreads();
  for (int idx = t; idx < 768; idx += 256) {
    int h = idx >> 6, c = idx & 63;
    qs[idx] = bf2f(isa ? QAb[(long long)n * 768 + idx] : QRb[(long long)n * 768 + idx]);
    ks[idx] = bf2f(isa ? KVAb[(long long)n * 1536 + h * 128 + c] : KVRb[(long long)n * 1536 + h * 128 + c]);
    vs[idx] = bf2f(isa ? KVAb[(long long)n * 1536 + h * 128 + 64 + c] : KVRb[(long long)n * 1536 + h * 128 + 64 + c]);
  }
  if (isa) {
    for (int idx = t; idx < 144; idx += 256) {
      int hp = idx / 3, x = idx % 3;
      float a = 0.f;
      for (int i = 0; i < 64; ++i) a += sv[i * 3 + x] * tfnq_wv[i * 48 + hp];
      qp[idx] = a + T[x];
    }
    for (int idx = t; idx < 432; idx += 256) {
      int o = idx / 3, x = idx % 3;
      float a = 0.f;
      for (int i = 0; i < 64; ++i) a += sv[i * 3 + x] * tfnkv_wv[i * 144 + o];
      float v = a + T[x];
      int h = o / 12, pp = o % 12;
      if (pp < 4) kp[(h * 4 + pp) * 3 + x] = v;
      else        vp[(h * 8 + (pp - 4)) * 3 + x] = v;
    }
  } else {
    for (int idx = t; idx < 144; idx += 256) {
      int hp = idx / 3, i = idx % 3;
      qp[idx] = R[i * 3 + 0] * QP[(long long)n * 144 + 0 + hp] +
                R[i * 3 + 1] * QP[(long long)n * 144 + 48 + hp] +
                R[i * 3 + 2] * QP[(long long)n * 144 + 96 + hp] + T[i];
    }
    for (int idx = t; idx < 432; idx += 256) {
      int hp = idx / 3, i = idx % 3;
      float v = R[i * 3 + 0] * KVP[(long long)n * 432 + 0 + hp] +
                R[i * 3 + 1] * KVP[(long long)n * 432 + 144 + hp] +
                R[i * 3 + 2] * KVP[(long long)n * 432 + 288 + hp] + T[i];
      int h = hp / 12, pp = hp % 12;
      if (pp < 4) kp[(h * 4 + pp) * 3 + i] = v;
      else        vp[(h * 8 + (pp - 4)) * 3 + i] = v;
    }
  }
  __syncthreads();
  const float sq = 0.07216878364870322f;  // sqrt(1/192)
  for (int idx = t; idx < 1152; idx += 256) {
    int h = idx / 96, c = idx % 96;
    float qv = (c < 64) ? sq * qs[h * 64 + c] : ((c < 76) ? shw[h] * qp[h * 12 + (c - 64)] : 0.f);
    float kv = (c < 64) ? ks[h * 64 + c]      : ((c < 76) ? kp[h * 12 + (c - 64)] : 0.f);
    float vv = (c < 64) ? vs[h * 64 + c]      : ((c < 88) ? vp[h * 24 + (c - 64)] : 0.f);
    long long base = ((long long)n * 12 + h) * 96 + c;
    Qcat[base] = f2bf(qv);
    Kcat[base] = f2bf(kv);
    Vt[((long long)h * 96 + c) * 768 + n] = f2bf(vv);   // transposed write (L2-resident)
  }
  if (t < 24) {
    int h = t >> 1, which = t & 1;
    const float* p = which ? kp : qp;
    float s2 = 0.f;
#pragma unroll
    for (int d = 0; d < 12; ++d) { float x = p[h * 12 + d]; s2 += x * x; }
    float val = 0.5f * shw[h] * s2;
    if (which) rk[h * 768 + n] = val;
    else       rq[h * 768 + n] = val;
  }
}

// ====== mega2: 8 rows/block (1152 blocks) — logits + softmax + A-write + fused PV ======
__global__ __launch_bounds__(256) void mega2(float* wsf, const float* __restrict__ mask) {
  __shared__ __align__(16) char lds[26112];
  const int t = threadIdx.x;
  const unsigned short* Qcat = (const unsigned short*)(wsf + OFF_QCAT);
  const unsigned short* Kcat = (const unsigned short*)(wsf + OFF_KCAT);
  const unsigned short* Bb   = (const unsigned short*)(wsf + OFF_BB);
  const unsigned short* VcatT= (const unsigned short*)(wsf + OFF_VCATT);
  const float* rq = wsf + OFF_RQ;
  const float* rk = wsf + OFF_RK;
  unsigned short* Abf   = (unsigned short*)(wsf + OFF_ABF);
  unsigned short* RESF  = (unsigned short*)(wsf + OFF_RESF);
  unsigned short* ATOMF = (unsigned short*)(wsf + OFF_ATOMF);
  float* OPTRAW = wsf + OFF_OPTRAW;
  const int h = blockIdx.x / 96, r0 = (blockIdx.x % 96) * 8;   // 8 rows/block
  const int w = t >> 6, l = t & 63, l15 = l & 15, lg = l >> 4;
  unsigned short* SW = (unsigned short*)lds + w * 3200;   // [16][200] per wave (rows 8..15 zeroed)
  float* redm = (float*)(lds + 25600);                    // [4][8]
  float* reds = (float*)(lds + 25728);                    // [4][8]
  const bool vrow = (lg < 2);                             // lanes owning rows 0..7
  const int nrow = r0 + l15;
  const int nr = (nrow < 768) ? nrow : 767;               // clamp MFMA tail rows
  v8bf aq[3];
#pragma unroll
  for (int ks = 0; ks < 3; ++ks)
    aq[ks] = *(const v8bf*)(Qcat + ((long long)nr * 12 + h) * 96 + ks * 32 + lg * 8);
  v4f acc[12] = {};
#pragma unroll
  for (int cf = 0; cf < 12; ++cf) {
    int m = w * 192 + cf * 16 + l15;
    const unsigned short* kb = Kcat + ((long long)m * 12 + h) * 96 + lg * 8;
#pragma unroll
    for (int ks = 0; ks < 3; ++ks) {
      v8bf bv = *(const v8bf*)(kb + ks * 32);
      acc[cf] = __builtin_amdgcn_mfma_f32_16x16x32_bf16(aq[ks], bv, acc[cf], 0, 0, 0);
    }
  }
  // stage Bb tile (8 rows x 192 cols per wave), coalesced
#pragma unroll
  for (int it = 0; it < 3; ++it) {
    int chunk = it * 64 + l;                 // 0..191
    int row = chunk / 24, cc = (chunk % 24) * 8;
    *(uint4*)(SW + row * 200 + cc) =
        *(const uint4*)(Bb + ((long long)(h * 768 + r0 + row)) * 768 + w * 192 + cc);
  }
  __syncthreads();
  float rkm[12], mkm[12];
#pragma unroll
  for (int cf = 0; cf < 12; ++cf) {
    int m = w * 192 + cf * 16 + l15;
    rkm[cf] = rk[h * 768 + m];
    mkm[cf] = mask[m];
  }
  float rqn[4], mkn[4], mymax[4];
#pragma unroll
  for (int i = 0; i < 4; ++i) {
    int rl = lg * 4 + i;
    int gn = vrow ? (r0 + rl) : 0;
    rqn[i] = rq[h * 768 + gn];
    mkn[i] = mask[gn];
    mymax[i] = -3.0e38f;
  }
#pragma unroll
  for (int cf = 0; cf < 12; ++cf)
#pragma unroll
    for (int i = 0; i < 4; ++i) {
      int rl = lg * 4 + i;
      float bbv = vrow ? bf2f(SW[rl * 200 + cf * 16 + l15]) : 0.f;
      float v = acc[cf][i] + bbv - rqn[i] - rkm[cf]
              + 100000.0f * (mkn[i] * mkm[cf] - 1.0f);
      acc[cf][i] = v;
      mymax[i] = fmaxf(mymax[i], v);
    }
#pragma unroll
  for (int off = 1; off < 16; off <<= 1)
#pragma unroll
    for (int i = 0; i < 4; ++i) mymax[i] = fmaxf(mymax[i], __shfl_xor(mymax[i], off, 64));
  if (l15 == 0 && vrow) {
#pragma unroll
    for (int i = 0; i < 4; ++i) redm[w * 8 + lg * 4 + i] = mymax[i];
  }
  __syncthreads();
  float mx[4], mysum[4];
#pragma unroll
  for (int i = 0; i < 4; ++i) {
    int rl = lg * 4 + i;
    mx[i] = vrow ? fmaxf(fmaxf(redm[rl], redm[8 + rl]), fmaxf(redm[16 + rl], redm[24 + rl]))
                 : 3.0e38f;   // invalid rows -> exp underflows to 0
    mysum[i] = 0.f;
  }
#pragma unroll
  for (int cf = 0; cf < 12; ++cf)
#pragma unroll
    for (int i = 0; i < 4; ++i) {
      float e = __expf(acc[cf][i] - mx[i]);
      acc[cf][i] = e;
      mysum[i] += e;
    }
#pragma unroll
  for (int off = 1; off < 16; off <<= 1)
#pragma unroll
    for (int i = 0; i < 4; ++i) mysum[i] += __shfl_xor(mysum[i], off, 64);
  if (l15 == 0 && vrow) {
#pragma unroll
    for (int i = 0; i < 4; ++i) reds[w * 8 + lg * 4 + i] = mysum[i];
  }
  __syncthreads();
  float inv[4];
#pragma unroll
  for (int i = 0; i < 4; ++i) {
    int rl = lg * 4 + i;
    inv[i] = vrow ? 1.0f / (reds[rl] + reds[8 + rl] + reds[16 + rl] + reds[24 + rl]) : 0.f;
  }
#pragma unroll
  for (int cf = 0; cf < 12; ++cf)
#pragma unroll
    for (int i = 0; i < 4; ++i) {
      int rl = lg * 4 + i;
      SW[rl * 200 + cf * 16 + l15] = vrow ? f2bf(acc[cf][i] * inv[i]) : 0;
    }
  __syncthreads();
  // write A (bf16, [h][n][m]) for attn_pair — 8 rows
#pragma unroll
  for (int it = 0; it < 3; ++it) {
    int chunk = it * 64 + l;
    int row = chunk / 24, cc = (chunk % 24) * 8;
    *(uint4*)(Abf + ((long long)(h * 768 + r0 + row)) * 768 + w * 192 + cc) =
        *(const uint4*)(SW + row * 200 + cc);
  }
  // ---- fused A@Vcat (split-K: wave w owns k in [w*192, w*192+192)) ----
  const unsigned short* vbase = VcatT + (long long)h * 96 * 768 + w * 192 + lg * 8;
  v4f acc2[6] = {};
#pragma unroll
  for (int kk = 0; kk < 192; kk += 32) {
    v8bf av = *(const v8bf*)(SW + l15 * 200 + kk + lg * 8);
#pragma unroll
    for (int cf = 0; cf < 6; ++cf) {
      v8bf bv = *(const v8bf*)(vbase + (long long)(cf * 16 + l15) * 768 + kk);
      acc2[cf] = __builtin_amdgcn_mfma_f32_16x16x32_bf16(av, bv, acc2[cf], 0, 0, 0);
    }
  }
  __syncthreads();
  v4f (*PS)[64] = (v4f (*)[64])lds;    // overlays SW (done with it)
#pragma unroll
  for (int cf = 0; cf < 6; ++cf) PS[w * 6 + cf][l] = acc2[cf];
  __syncthreads();
  for (int cf = w; cf < 6; cf += 4) {
    v4f sv = PS[cf][l] + PS[6 + cf][l] + PS[12 + cf][l] + PS[18 + cf][l];
    int c = cf * 16 + l15;
    if (vrow) {
      int rb = r0 + lg * 4;
#pragma unroll
      for (int i = 0; i < 4; ++i) {
        int n = rb + i;
        float v = sv[i];
        if (c < 64) {
          unsigned short b = f2bf(v);
          RESF[(long long)n * 1536 + h * 64 + c] = b;
          ATOMF[(long long)n * 1280 + h * 64 + c] = b;
        } else if (c < 88) {
          OPTRAW[(long long)n * 288 + h * 24 + (c - 64)] = v;
        }
      }
    }
  }
}

// ================= mega3: attn_pair (768) || finalize (768) =================
__global__ __launch_bounds__(256) void mega3(
    float* wsf, const float* __restrict__ rot, const float* __restrict__ trans,
    const float* __restrict__ tfno_wv, float* __restrict__ out)
{
  const int t = threadIdx.x;
  unsigned short* RESF  = (unsigned short*)(wsf + OFF_RESF);
  unsigned short* ATOMF = (unsigned short*)(wsf + OFF_ATOMF);
  if (blockIdx.x < 768) {
    __shared__ __align__(16) v4f PS[8][64];
    const unsigned short* Abf = (const unsigned short*)(wsf + OFF_ABF);
    const unsigned short* PZT = (const unsigned short*)(wsf + OFF_PZT);
    const int w = t >> 6, l = t & 63, l15 = l & 15, lg = l >> 4;
    const int n = blockIdx.x;
    const int hh = (l15 < 12) ? l15 : 0;
    const unsigned short* arow = Abf + ((long long)hh * 768 + n) * 768 + lg * 8;
    const unsigned short* pz = PZT + (long long)n * 32 * 768 + lg * 8;
    v4f acc[2] = {};
    for (int k0 = w * 192; k0 < w * 192 + 192; k0 += 32) {
      v8bf av = *(const v8bf*)(arow + k0);
#pragma unroll
      for (int cf = 0; cf < 2; ++cf) {
        v8bf bv = *(const v8bf*)(pz + (long long)(cf * 16 + l15) * 768 + k0);
        acc[cf] = __builtin_amdgcn_mfma_f32_16x16x32_bf16(av, bv, acc[cf], 0, 0, 0);
      }
    }
    PS[w * 2 + 0][l] = acc[0];
    PS[w * 2 + 1][l] = acc[1];
    __syncthreads();
    if (t < 128) {
      int cf = t >> 6, ll = t & 63;
      v4f sv = PS[cf][ll] + PS[2 + cf][ll] + PS[4 + cf][ll] + PS[6 + cf][ll];
      int zc = cf * 16 + (ll & 15);
#pragma unroll
      for (int i = 0; i < 4; ++i) {
        int hd = (ll >> 4) * 4 + i;
        if (hd < 12) {
          unsigned short b = f2bf(sv[i]);
          RESF[(long long)n * 1536 + 1152 + hd * 32 + zc] = b;
          ATOMF[(long long)n * 1280 + 864 + hd * 32 + zc] = b;
        }
      }
    }
    return;
  }
  // ---- finalize ----
  {
    const int n = blockIdx.x - 768;
    const float* OPTRAW = wsf + OFF_OPTRAW;
    const int* ISA = (const int*)wsf;
    const bool isa = ISA[n] != 0;
    __shared__ float R[9], T[3], opt2[96][3], norml[96];
    if (t < 9) R[t] = rot[(size_t)n * 9 + t];
    if (t < 3) T[t] = trans[(size_t)n * 3 + t];
    __syncthreads();
    for (int idx = t; idx < 288; idx += 256) {
      int hp = idx / 3, i = idx % 3;
      float x = OPTRAW[(size_t)n * 288 + hp * 3 + 0] - T[0];
      float y = OPTRAW[(size_t)n * 288 + hp * 3 + 1] - T[1];
      float z = OPTRAW[(size_t)n * 288 + hp * 3 + 2] - T[2];
      opt2[hp][i] = R[0 + i] * x + R[3 + i] * y + R[6 + i] * z;  // rot^T
    }
    __syncthreads();
    if (t < 96)
      norml[t] = sqrtf(opt2[t][0] * opt2[t][0] + opt2[t][1] * opt2[t][1] +
                       opt2[t][2] * opt2[t][2] + 1e-8f);
    __syncthreads();
    const long long rb = (long long)n * 1536;
    const long long ab = (long long)n * 1280;
    for (int idx = t; idx < 288; idx += 256) {
      int x = idx / 96, hp = idx % 96;
      RESF[rb + 768 + idx] = f2bf(opt2[hp][x]);
    }
    for (int idx = t; idx < 96; idx += 256) {
      unsigned short b = f2bf(norml[idx]);
      RESF[rb + 1056 + idx] = b;
      ATOMF[ab + 768 + idx] = b;
    }
    if (isa) {
      for (int idx = t; idx < 192; idx += 256) {
        int o = idx / 3, x = idx % 3;
        float a = 0.f;
        for (int p = 0; p < 96; ++p) a += opt2[p][x] * tfno_wv[p * 64 + o];
        out[(size_t)n * 384 + 192 + idx] = a;
      }
    }
  }
}

// ================= out GEMMs (predicated writes into d_out) =================
__global__ __launch_bounds__(256) void outg(float* wsf, const float* __restrict__ bout,
                                            float* __restrict__ out) {
  __shared__ __align__(16) char lds[16384];
  const int g = blockIdx.x;
  const int bt = g / 9, xt = g % 9;
  const int* ISA = (const int*)wsf;
  if (xt < 6)
    gemm16(lds, (const unsigned short*)(wsf + OFF_RESF), 1536,
           (const unsigned short*)(wsf + OFF_WOUTT), 1536, 384, bout, 2,
           nullptr, nullptr, 0, 384, xt * 64, bt * 16, ISA, out);
  else
    gemm16(lds, (const unsigned short*)(wsf + OFF_ATOMF), 1280,
           (const unsigned short*)(wsf + OFF_TFNOT), 1280, 320, nullptr, 3,
           nullptr, nullptr, 0, 192, (xt - 6) * 64, bt * 16, ISA, out);
}

extern "C" void kernel_launch(void* const* d_in, const int* in_sizes, int n_in,
                              void* d_out, int out_size, void* d_ws, size_t ws_size,
                              hipStream_t stream) {
  (void)in_sizes; (void)n_in; (void)out_size; (void)ws_size;
  const float* s      = (const float*)d_in[0];
  const float* z      = (const float*)d_in[1];
  const float* rot    = (const float*)d_in[2];
  const float* trans  = (const float*)d_in[3];
  const float* mask   = (const float*)d_in[4];
  const float* wq     = (const float*)d_in[6];
  const float* bq     = (const float*)d_in[7];
  const float* wkv    = (const float*)d_in[8];
  const float* bkv    = (const float*)d_in[9];
  const float* wqp    = (const float*)d_in[10];
  const float* bqp    = (const float*)d_in[11];
  const float* wkvp   = (const float*)d_in[12];
  const float* bkvp   = (const float*)d_in[13];
  const float* wb     = (const float*)d_in[14];
  const float* bb     = (const float*)d_in[15];
  const float* wdz    = (const float*)d_in[16];
  const float* bdz    = (const float*)d_in[17];
  const float* head_w = (const float*)d_in[18];
  const float* wout   = (const float*)d_in[19];
  const float* bout   = (const float*)d_in[20];
  const float* tfnq_ws  = (const float*)d_in[21];
  const float* tfnq_wv  = (const float*)d_in[22];
  const float* tfnkv_ws = (const float*)d_in[23];
  const float* tfnkv_wv = (const float*)d_in[24];
  const float* tfno_ws  = (const float*)d_in[25];
  const float* tfno_wv  = (const float*)d_in[26];

  float* wsf = (float*)d_ws;

  prep0<<<2797, 256, 0, stream>>>(wsf, s, wq, wkv, wqp, wkvp, tfnq_ws, tfnkv_ws,
                                  wout, tfno_ws, wb, wdz, bb, bdz,
                                  (const unsigned int*)d_in[5]);
  mega1<<<8544, 256, 0, stream>>>(wsf, z, bq, bkv, bqp, bkvp);
  prep_qkv<<<768, 256, 0, stream>>>(wsf, s, rot, trans, head_w, tfnq_wv, tfnkv_wv);
  mega2<<<1152, 256, 0, stream>>>(wsf, mask);
  mega3<<<1536, 256, 0, stream>>>(wsf, rot, trans, tfno_wv, (float*)d_out);
  outg<<<432, 256, 0, stream>>>(wsf, bout, (float*)d_out);
}

// Round 10
// 186.125 us; speedup vs baseline: 1.1659x; 1.1659x over previous
//
#include <hip/hip_runtime.h>
#include <hip/hip_bf16.h>

static constexpr int NN = 768;

typedef short v8bf __attribute__((ext_vector_type(8)));   // 8 bf16 (4 VGPRs)
typedef float v4f  __attribute__((ext_vector_type(4)));

__device__ __forceinline__ unsigned short f2bf(float f) {
  unsigned u = __float_as_uint(f);
  u += 0x7fffu + ((u >> 16) & 1u);          // RNE
  return (unsigned short)(u >> 16);
}
__device__ __forceinline__ float bf2f(unsigned short s) {
  return __uint_as_float(((unsigned)s) << 16);
}

// -------- workspace layout (float units; all multiples of 64) --------
static constexpr size_t OFF_ISA    = 0;          // 1024 ints
static constexpr size_t OFF_WCT    = 1024;       // 48x128 bf16
static constexpr size_t OFF_BCAT   = 4096;       // 48 f32
static constexpr size_t OFF_SBF    = 4160;       // 768x384 bf16
static constexpr size_t OFF_WQT    = 151616;     // 768x384 bf16
static constexpr size_t OFF_WKVT   = 299072;     // 1536x384 bf16
static constexpr size_t OFF_WQPT   = 593984;     // 192x384 bf16 (144 used)
static constexpr size_t OFF_WKVPT  = 630848;     // 448x384 bf16 (432 used)
static constexpr size_t OFF_TFNQT  = 716864;     // 768x256 bf16 (K=192 + zero pad)
static constexpr size_t OFF_TFNKVT = 815168;     // 1536x256 bf16
static constexpr size_t OFF_WOUTT  = 1011776;    // 384x1536 bf16
static constexpr size_t OFF_TFNOT  = 1306688;    // 192x1280 bf16 (K=1248 + zero pad)
static constexpr size_t OFF_QR     = 1429568;    // 768x768 bf16
static constexpr size_t OFF_KVR    = 1724480;    // 768x1536 bf16
static constexpr size_t OFF_QP     = 2314304;    // 768x144 f32
static constexpr size_t OFF_KVP    = 2424896;    // 768x432 f32
static constexpr size_t OFF_QA     = 2756672;    // 768x768 bf16
static constexpr size_t OFF_KVA    = 3051584;    // 768x1536 bf16
static constexpr size_t OFF_QCAT   = 3641408;    // 768x12x96 bf16
static constexpr size_t OFF_KCAT   = 4083776;    // 768x12x96 bf16
static constexpr size_t OFF_RQ     = 4526144;    // 12x768 f32
static constexpr size_t OFF_RK     = 4535360;    // 12x768 f32
static constexpr size_t OFF_VCATT  = 4986944;    // 12x96x768 bf16
static constexpr size_t OFF_BB     = 5429312;    // 12x768x768 bf16 ([h][n][m])
static constexpr size_t OFF_PZT    = 8968256;    // 768x32x768 bf16
static constexpr size_t OFF_ABF    = 18405440;   // 12x768x768 bf16 ([h][n][m])
static constexpr size_t OFF_OPTRAW = 21944384;   // 768x288 f32
static constexpr size_t OFF_RESF   = 22165568;   // 768x1536 bf16
static constexpr size_t OFF_ATOMF  = 22755392;   // 768x1280 bf16 (1248 used)

// ================= prep0: detect + wcat + all weight converts =================
__device__ void transpose_cv(const float* __restrict__ src, unsigned short* __restrict__ dst,
                             int K, int Kp, int N, int ky, int nx) {
  __shared__ float tl[32][33];
  const int k0 = ky * 32, n0 = nx * 32;
  const int tx = threadIdx.x & 31, ty = threadIdx.x >> 5;
  for (int it = 0; it < 4; ++it) {
    int r = ty + it * 8;
    float v = 0.f;
    if (k0 + r < K && n0 + tx < N) v = src[(long long)(k0 + r) * N + n0 + tx];
    tl[r][tx] = v;
  }
  __syncthreads();
  for (int it = 0; it < 4; ++it) {
    int r = ty + it * 8;
    if (n0 + r < N && k0 + tx < Kp)
      dst[(long long)(n0 + r) * Kp + k0 + tx] = f2bf(tl[tx][r]);
  }
}

__global__ __launch_bounds__(256) void prep0(
    float* wsf, const float* s, const float* wq, const float* wkv,
    const float* wqp, const float* wkvp, const float* tfnq_ws,
    const float* tfnkv_ws, const float* wout, const float* tfno_ws,
    const float* wb, const float* wdz, const float* bb, const float* bdz,
    const unsigned int* isa_raw)
{
  const int bx = blockIdx.x, t = threadIdx.x;
  if (bx < 288)       { int g = bx;        transpose_cv(wq,      (unsigned short*)(wsf+OFF_WQT),    384, 384, 768,  g/24, g%24); return; }
  else if (bx < 864)  { int g = bx-288;    transpose_cv(wkv,     (unsigned short*)(wsf+OFF_WKVT),   384, 384, 1536, g/48, g%48); return; }
  else if (bx < 924)  { int g = bx-864;    transpose_cv(wqp,     (unsigned short*)(wsf+OFF_WQPT),   384, 384, 144,  g/5,  g%5);  return; }
  else if (bx < 1092) { int g = bx-924;    transpose_cv(wkvp,    (unsigned short*)(wsf+OFF_WKVPT),  384, 384, 432,  g/14, g%14); return; }
  else if (bx < 1284) { int g = bx-1092;   transpose_cv(tfnq_ws, (unsigned short*)(wsf+OFF_TFNQT),  192, 256, 768,  g/24, g%24); return; }
  else if (bx < 1668) { int g = bx-1284;   transpose_cv(tfnkv_ws,(unsigned short*)(wsf+OFF_TFNKVT), 192, 256, 1536, g/48, g%48); return; }
  else if (bx < 2244) { int g = bx-1668;   transpose_cv(wout,    (unsigned short*)(wsf+OFF_WOUTT),  1536,1536,384,  g/12, g%12); return; }
  else if (bx < 2484) { int g = bx-2244;   transpose_cv(tfno_ws, (unsigned short*)(wsf+OFF_TFNOT),  1248,1280,192,  g/6,  g%6);  return; }
  else if (bx < 2772) {
    long long base = (long long)(bx - 2484) * 1024 + t * 4;
    float4 v = *(const float4*)(s + base);
    unsigned short tmp[4] = {f2bf(v.x), f2bf(v.y), f2bf(v.z), f2bf(v.w)};
    *(uint2*)((unsigned short*)(wsf + OFF_SBF) + base) = *(uint2*)tmp;
    return;
  } else if (bx < 2773) {
    __shared__ int notint, notfloat;
    int* ISA = (int*)wsf;
    if (t == 0) { notint = 0; notfloat = 0; }
    __syncthreads();
    if (t < 192) {
      unsigned v = isa_raw[t];
      if (v > 1u) atomicOr(&notint, 1);
      if (v != 0u && v != 0x3F800000u) atomicOr(&notfloat, 1);
    }
    __syncthreads();
    const int mode = (!notint) ? 0 : ((!notfloat) ? 1 : 2);
    for (int n = t; n < NN; n += 256) {
      int val;
      if (mode == 2) val = (((const unsigned char*)isa_raw)[n] != 0);
      else           val = (isa_raw[n] != 0u);
      ISA[n] = val;
    }
    return;
  } else {
    const float rs3 = 0.57735026918962576f;
    unsigned short* WCT = (unsigned short*)(wsf + OFF_WCT);
    float* bcat = wsf + OFF_BCAT;
    int idx = (bx - 2773) * 256 + t;
    if (idx < 48 * 128) {
      int o = idx >> 7, k = idx & 127;
      float v = 0.f;
      if (o < 12) v = rs3 * wb[k * 12 + o];
      else if (o < 44) v = wdz[k * 32 + (o - 12)];
      WCT[o * 128 + k] = f2bf(v);
    }
    if (bx == 2773 && t < 48)
      bcat[t] = (t < 12) ? rs3 * bb[t] : (t < 44 ? bdz[t - 12] : 0.f);
  }
}

// ================= gemm16: 16 rows x 64 cols, 4-wave split-K =================
__device__ __forceinline__ void gemm16(
    char* lds, const unsigned short* __restrict__ A, int lda,
    const unsigned short* __restrict__ BT, int ldb, int KQ,
    const float* __restrict__ bias, int mode,
    float* Cf, unsigned short* Cb, int ldc, int Nc, int colb, int row0,
    const int* __restrict__ ISA, float* outp)
{
  v4f (*PS)[4][64] = (v4f (*)[4][64])lds;
  const int t = threadIdx.x, w = t >> 6, l = t & 63, l15 = l & 15, lg = l >> 4;
  const int rowA = row0 + l15;
  v4f acc[4] = {};
  const unsigned short* ap = A + (long long)rowA * lda + lg * 8;
  const int kend = (w + 1) * KQ;
  for (int k0 = w * KQ; k0 < kend; k0 += 32) {
    v8bf av = *(const v8bf*)(ap + k0);
#pragma unroll
    for (int cf = 0; cf < 4; ++cf) {
      v8bf bv = *(const v8bf*)(BT + (long long)(colb + cf * 16 + l15) * ldb + k0 + lg * 8);
      acc[cf] = __builtin_amdgcn_mfma_f32_16x16x32_bf16(av, bv, acc[cf], 0, 0, 0);
    }
  }
#pragma unroll
  for (int cf = 0; cf < 4; ++cf) PS[w][cf][l] = acc[cf];
  __syncthreads();
  const int cf = w;
  v4f sv = PS[0][cf][l] + PS[1][cf][l] + PS[2][cf][l] + PS[3][cf][l];
  const int c = colb + cf * 16 + l15;
  if (c < Nc) {
    float bvs = bias ? bias[c] : 0.f;
#pragma unroll
    for (int i = 0; i < 4; ++i) {
      int r = row0 + lg * 4 + i;
      float v = sv[i] + bvs;
      if (mode == 0)      Cf[(long long)r * ldc + c] = v;
      else if (mode == 1) Cb[(long long)r * ldc + c] = f2bf(v);
      else if (mode == 2) { if (!ISA[r]) outp[r * 384 + c] = v; }
      else                { if ( ISA[r]) outp[r * 384 + c] = v; }
    }
  }
}

// ================= mega1: zpass direct-reg (4608) || projection GEMMs (3936) =========
__global__ __launch_bounds__(256) void mega1(
    float* wsf, const float* __restrict__ z,
    const float* bq, const float* bkv, const float* bqp, const float* bkvp)
{
  __shared__ __align__(16) char lds[23296];
  const int t = threadIdx.x;
  if (blockIdx.x < 4608) {
    float* Sout = (float*)lds;
    const unsigned short* WCT = (const unsigned short*)(wsf + OFF_WCT);
    const float* bcat = wsf + OFF_BCAT;
    unsigned short* Bb  = (unsigned short*)(wsf + OFF_BB);
    unsigned short* PZT = (unsigned short*)(wsf + OFF_PZT);
    const long long row0 = (long long)blockIdx.x * 128;
    const int w = t >> 6, l = t & 63, l15 = l & 15, lg = l >> 4;
    v8bf bvv[4][3];
#pragma unroll
    for (int ks = 0; ks < 4; ++ks)
#pragma unroll
      for (int cf = 0; cf < 3; ++cf)
        bvv[ks][cf] = *(const v8bf*)(WCT + (cf * 16 + l15) * 128 + ks * 32 + lg * 8);
    v4f acc[2][3] = {};
#pragma unroll
    for (int rf = 0; rf < 2; ++rf) {
      const float* zrow = z + (row0 + w * 32 + rf * 16 + l15) * 128 + lg * 8;
#pragma unroll
      for (int ks = 0; ks < 4; ++ks) {
        float4 a0 = *(const float4*)(zrow + ks * 32);
        float4 a1 = *(const float4*)(zrow + ks * 32 + 4);
        unsigned short tmp[8] = {f2bf(a0.x), f2bf(a0.y), f2bf(a0.z), f2bf(a0.w),
                                 f2bf(a1.x), f2bf(a1.y), f2bf(a1.z), f2bf(a1.w)};
        v8bf av = *(const v8bf*)tmp;
#pragma unroll
        for (int cf = 0; cf < 3; ++cf)
          acc[rf][cf] = __builtin_amdgcn_mfma_f32_16x16x32_bf16(av, bvv[ks][cf], acc[rf][cf], 0, 0, 0);
      }
    }
#pragma unroll
    for (int rf = 0; rf < 2; ++rf)
#pragma unroll
      for (int cf = 0; cf < 3; ++cf) {
        int o = cf * 16 + l15;
#pragma unroll
        for (int i = 0; i < 4; ++i) {
          int m = w * 32 + rf * 16 + lg * 4 + i;
          Sout[o * 132 + m] = acc[rf][cf][i];
        }
      }
    __syncthreads();
    const int n = blockIdx.x / 6;
    const int m0 = (blockIdx.x % 6) * 128;
    for (int idx = t; idx < 44 * 8; idx += 256) {
      int o = idx >> 3, seg = idx & 7;
      float bias = bcat[o];
      unsigned short tmp[16];
#pragma unroll
      for (int j = 0; j < 16; ++j) tmp[j] = f2bf(Sout[o * 132 + seg * 16 + j] + bias);
      unsigned short* gp;
      if (o < 12) gp = Bb + ((long long)o * 768 + n) * 768 + m0 + seg * 16;
      else        gp = PZT + ((long long)n * 32 + (o - 12)) * 768 + m0 + seg * 16;
      *(uint4*)gp = *(uint4*)tmp;
      *(uint4*)(gp + 8) = *(uint4*)(tmp + 8);
    }
    return;
  }
  // ---- projection GEMMs ----
  const int g = blockIdx.x - 4608;
  const int bt = g / 82, xt = g % 82;
  const unsigned short* SBF = (const unsigned short*)(wsf + OFF_SBF);
  const unsigned short* BT; const float* bias; int ldb, KQ, mode, ldc, Nc, colb;
  float* Cf = nullptr; unsigned short* Cb = nullptr;
  if (xt < 12)      { BT=(const unsigned short*)(wsf+OFF_WQT);    bias=bq;     ldb=384; KQ=96; Cb=(unsigned short*)(wsf+OFF_QR);  ldc=768;  Nc=768;  colb=xt*64;      mode=1; }
  else if (xt < 36) { BT=(const unsigned short*)(wsf+OFF_WKVT);   bias=bkv;    ldb=384; KQ=96; Cb=(unsigned short*)(wsf+OFF_KVR); ldc=1536; Nc=1536; colb=(xt-12)*64; mode=1; }
  else if (xt < 39) { BT=(const unsigned short*)(wsf+OFF_WQPT);   bias=bqp;    ldb=384; KQ=96; Cf=wsf+OFF_QP;                     ldc=144;  Nc=144;  colb=(xt-36)*64; mode=0; }
  else if (xt < 46) { BT=(const unsigned short*)(wsf+OFF_WKVPT);  bias=bkvp;   ldb=384; KQ=96; Cf=wsf+OFF_KVP;                    ldc=432;  Nc=432;  colb=(xt-39)*64; mode=0; }
  else if (xt < 58) { BT=(const unsigned short*)(wsf+OFF_TFNQT);  bias=nullptr;ldb=256; KQ=64; Cb=(unsigned short*)(wsf+OFF_QA);  ldc=768;  Nc=768;  colb=(xt-46)*64; mode=1; }
  else              { BT=(const unsigned short*)(wsf+OFF_TFNKVT); bias=nullptr;ldb=256; KQ=64; Cb=(unsigned short*)(wsf+OFF_KVA); ldc=1536; Nc=1536; colb=(xt-58)*64; mode=1; }
  gemm16(lds, SBF, 384, BT, ldb, KQ, bias, mode, Cf, Cb, ldc, Nc, colb, bt * 16, nullptr, nullptr);
}

// ================= prep_qkv (writes VcatT transposed directly) =================
__global__ __launch_bounds__(256) void prep_qkv(
    float* wsf, const float* __restrict__ s,
    const float* __restrict__ rot, const float* __restrict__ trans,
    const float* __restrict__ head_w,
    const float* __restrict__ tfnq_wv, const float* __restrict__ tfnkv_wv)
{
  const int n = blockIdx.x, t = threadIdx.x;
  const int* ISA = (const int*)wsf;
  const unsigned short* QRb  = (const unsigned short*)(wsf + OFF_QR);
  const unsigned short* KVRb = (const unsigned short*)(wsf + OFF_KVR);
  const unsigned short* QAb  = (const unsigned short*)(wsf + OFF_QA);
  const unsigned short* KVAb = (const unsigned short*)(wsf + OFF_KVA);
  const float* QP  = wsf + OFF_QP;
  const float* KVP = wsf + OFF_KVP;
  unsigned short* Qcat = (unsigned short*)(wsf + OFF_QCAT);
  unsigned short* Kcat = (unsigned short*)(wsf + OFF_KCAT);
  unsigned short* Vt   = (unsigned short*)(wsf + OFF_VCATT);
  float* rq = wsf + OFF_RQ;
  float* rk = wsf + OFF_RK;
  const bool isa = ISA[n] != 0;
  __shared__ float R[9], T[3], shw[12], sv[192];
  __shared__ float qs[768], ks[768], vs[768], qp[144], kp[144], vp[288];
  if (t < 9) R[t] = rot[n * 9 + t];
  if (t < 3) T[t] = trans[n * 3 + t];
  if (t >= 16 && t < 28)
    shw[t - 16] = log1pf(__expf(head_w[t - 16])) * 0.13608276348795434f;
  if (isa && t >= 32 && t < 224) sv[t - 32] = s[(size_t)n * 384 + 192 + (t - 32)];
  __syncthreads();
  for (int idx = t; idx < 768; idx += 256) {
    int h = idx >> 6, c = idx & 63;
    qs[idx] = bf2f(isa ? QAb[(long long)n * 768 + idx] : QRb[(long long)n * 768 + idx]);
    ks[idx] = bf2f(isa ? KVAb[(long long)n * 1536 + h * 128 + c] : KVRb[(long long)n * 1536 + h * 128 + c]);
    vs[idx] = bf2f(isa ? KVAb[(long long)n * 1536 + h * 128 + 64 + c] : KVRb[(long long)n * 1536 + h * 128 + 64 + c]);
  }
  if (isa) {
    for (int idx = t; idx < 144; idx += 256) {
      int hp = idx / 3, x = idx % 3;
      float a = 0.f;
      for (int i = 0; i < 64; ++i) a += sv[i * 3 + x] * tfnq_wv[i * 48 + hp];
      qp[idx] = a + T[x];
    }
    for (int idx = t; idx < 432; idx += 256) {
      int o = idx / 3, x = idx % 3;
      float a = 0.f;
      for (int i = 0; i < 64; ++i) a += sv[i * 3 + x] * tfnkv_wv[i * 144 + o];
      float v = a + T[x];
      int h = o / 12, pp = o % 12;
      if (pp < 4) kp[(h * 4 + pp) * 3 + x] = v;
      else        vp[(h * 8 + (pp - 4)) * 3 + x] = v;
    }
  } else {
    for (int idx = t; idx < 144; idx += 256) {
      int hp = idx / 3, i = idx % 3;
      qp[idx] = R[i * 3 + 0] * QP[(long long)n * 144 + 0 + hp] +
                R[i * 3 + 1] * QP[(long long)n * 144 + 48 + hp] +
                R[i * 3 + 2] * QP[(long long)n * 144 + 96 + hp] + T[i];
    }
    for (int idx = t; idx < 432; idx += 256) {
      int hp = idx / 3, i = idx % 3;
      float v = R[i * 3 + 0] * KVP[(long long)n * 432 + 0 + hp] +
                R[i * 3 + 1] * KVP[(long long)n * 432 + 144 + hp] +
                R[i * 3 + 2] * KVP[(long long)n * 432 + 288 + hp] + T[i];
      int h = hp / 12, pp = hp % 12;
      if (pp < 4) kp[(h * 4 + pp) * 3 + i] = v;
      else        vp[(h * 8 + (pp - 4)) * 3 + i] = v;
    }
  }
  __syncthreads();
  const float sq = 0.07216878364870322f;  // sqrt(1/192)
  for (int idx = t; idx < 1152; idx += 256) {
    int h = idx / 96, c = idx % 96;
    float qv = (c < 64) ? sq * qs[h * 64 + c] : ((c < 76) ? shw[h] * qp[h * 12 + (c - 64)] : 0.f);
    float kv = (c < 64) ? ks[h * 64 + c]      : ((c < 76) ? kp[h * 12 + (c - 64)] : 0.f);
    float vv = (c < 64) ? vs[h * 64 + c]      : ((c < 88) ? vp[h * 24 + (c - 64)] : 0.f);
    long long base = ((long long)n * 12 + h) * 96 + c;
    Qcat[base] = f2bf(qv);
    Kcat[base] = f2bf(kv);
    Vt[((long long)h * 96 + c) * 768 + n] = f2bf(vv);   // transposed write (L2-resident)
  }
  if (t < 24) {
    int h = t >> 1, which = t & 1;
    const float* p = which ? kp : qp;
    float s2 = 0.f;
#pragma unroll
    for (int d = 0; d < 12; ++d) { float x = p[h * 12 + d]; s2 += x * x; }
    float val = 0.5f * shw[h] * s2;
    if (which) rk[h * 768 + n] = val;
    else       rq[h * 768 + n] = val;
  }
}

// ====== mega2: logits + softmax + A-write + fused A@Vcat (256 thr) ======
__global__ __launch_bounds__(256) void mega2(float* wsf, const float* __restrict__ mask) {
  __shared__ __align__(16) char lds[26112];
  const int t = threadIdx.x;
  const unsigned short* Qcat = (const unsigned short*)(wsf + OFF_QCAT);
  const unsigned short* Kcat = (const unsigned short*)(wsf + OFF_KCAT);
  const unsigned short* Bb   = (const unsigned short*)(wsf + OFF_BB);
  const unsigned short* VcatT= (const unsigned short*)(wsf + OFF_VCATT);
  const float* rq = wsf + OFF_RQ;
  const float* rk = wsf + OFF_RK;
  unsigned short* Abf   = (unsigned short*)(wsf + OFF_ABF);
  unsigned short* RESF  = (unsigned short*)(wsf + OFF_RESF);
  unsigned short* ATOMF = (unsigned short*)(wsf + OFF_ATOMF);
  float* OPTRAW = wsf + OFF_OPTRAW;
  const int h = blockIdx.x / 48, r0 = (blockIdx.x % 48) * 16;
  const int w = t >> 6, l = t & 63, l15 = l & 15, lg = l >> 4;
  unsigned short* SW = (unsigned short*)lds + w * 3200;   // [16][200] per wave
  float* redm = (float*)(lds + 25600);
  float* reds = (float*)(lds + 25856);
  const int nrow = r0 + l15;
  v8bf aq[3];
#pragma unroll
  for (int ks = 0; ks < 3; ++ks)
    aq[ks] = *(const v8bf*)(Qcat + ((long long)nrow * 12 + h) * 96 + ks * 32 + lg * 8);
  v4f acc[12] = {};
#pragma unroll
  for (int cf = 0; cf < 12; ++cf) {
    int m = w * 192 + cf * 16 + l15;
    const unsigned short* kb = Kcat + ((long long)m * 12 + h) * 96 + lg * 8;
#pragma unroll
    for (int ks = 0; ks < 3; ++ks) {
      v8bf bv = *(const v8bf*)(kb + ks * 32);
      acc[cf] = __builtin_amdgcn_mfma_f32_16x16x32_bf16(aq[ks], bv, acc[cf], 0, 0, 0);
    }
  }
#pragma unroll
  for (int it = 0; it < 6; ++it) {
    int chunk = it * 64 + l;
    int row = chunk / 24, cc = (chunk % 24) * 8;
    *(uint4*)(SW + row * 200 + cc) =
        *(const uint4*)(Bb + ((long long)(h * 768 + r0 + row)) * 768 + w * 192 + cc);
  }
  __syncthreads();
  float rkm[12], mkm[12];
#pragma unroll
  for (int cf = 0; cf < 12; ++cf) {
    int m = w * 192 + cf * 16 + l15;
    rkm[cf] = rk[h * 768 + m];
    mkm[cf] = mask[m];
  }
  float rqn[4], mkn[4], mymax[4];
#pragma unroll
  for (int i = 0; i < 4; ++i) {
    int gn = r0 + lg * 4 + i;
    rqn[i] = rq[h * 768 + gn];
    mkn[i] = mask[gn];
    mymax[i] = -3.0e38f;
  }
#pragma unroll
  for (int cf = 0; cf < 12; ++cf)
#pragma unroll
    for (int i = 0; i < 4; ++i) {
      float v = acc[cf][i] + bf2f(SW[(lg * 4 + i) * 200 + cf * 16 + l15])
              - rqn[i] - rkm[cf] + 100000.0f * (mkn[i] * mkm[cf] - 1.0f);
      acc[cf][i] = v;
      mymax[i] = fmaxf(mymax[i], v);
    }
#pragma unroll
  for (int off = 1; off < 16; off <<= 1)
#pragma unroll
    for (int i = 0; i < 4; ++i) mymax[i] = fmaxf(mymax[i], __shfl_xor(mymax[i], off, 64));
  if (l15 == 0) {
#pragma unroll
    for (int i = 0; i < 4; ++i) redm[w * 16 + lg * 4 + i] = mymax[i];
  }
  __syncthreads();
  float mx[4], mysum[4];
#pragma unroll
  for (int i = 0; i < 4; ++i) {
    int rl = lg * 4 + i;
    mx[i] = fmaxf(fmaxf(redm[rl], redm[16 + rl]), fmaxf(redm[32 + rl], redm[48 + rl]));
    mysum[i] = 0.f;
  }
#pragma unroll
  for (int cf = 0; cf < 12; ++cf)
#pragma unroll
    for (int i = 0; i < 4; ++i) {
      float e = __expf(acc[cf][i] - mx[i]);
      acc[cf][i] = e;
      mysum[i] += e;
    }
#pragma unroll
  for (int off = 1; off < 16; off <<= 1)
#pragma unroll
    for (int i = 0; i < 4; ++i) mysum[i] += __shfl_xor(mysum[i], off, 64);
  if (l15 == 0) {
#pragma unroll
    for (int i = 0; i < 4; ++i) reds[w * 16 + lg * 4 + i] = mysum[i];
  }
  __syncthreads();
  float inv[4];
#pragma unroll
  for (int i = 0; i < 4; ++i) {
    int rl = lg * 4 + i;
    inv[i] = 1.0f / (reds[rl] + reds[16 + rl] + reds[32 + rl] + reds[48 + rl]);
  }
#pragma unroll
  for (int cf = 0; cf < 12; ++cf)
#pragma unroll
    for (int i = 0; i < 4; ++i)
      SW[(lg * 4 + i) * 200 + cf * 16 + l15] = f2bf(acc[cf][i] * inv[i]);
  __syncthreads();
  // write A (bf16, [h][n][m]) for attn_pair
#pragma unroll
  for (int it = 0; it < 6; ++it) {
    int chunk = it * 64 + l;
    int row = chunk / 24, cc = (chunk % 24) * 8;
    *(uint4*)(Abf + ((long long)(h * 768 + r0 + row)) * 768 + w * 192 + cc) =
        *(const uint4*)(SW + row * 200 + cc);
  }
  // ---- fused A@Vcat (split-K: wave w owns k in [w*192, w*192+192)) ----
  const unsigned short* vbase = VcatT + (long long)h * 96 * 768 + w * 192 + lg * 8;
  v4f acc2[6] = {};
#pragma unroll
  for (int kk = 0; kk < 192; kk += 32) {
    v8bf av = *(const v8bf*)(SW + l15 * 200 + kk + lg * 8);
#pragma unroll
    for (int cf = 0; cf < 6; ++cf) {
      v8bf bv = *(const v8bf*)(vbase + (long long)(cf * 16 + l15) * 768 + kk);
      acc2[cf] = __builtin_amdgcn_mfma_f32_16x16x32_bf16(av, bv, acc2[cf], 0, 0, 0);
    }
  }
  __syncthreads();
  v4f (*PS)[64] = (v4f (*)[64])lds;    // overlays SW (done with it)
#pragma unroll
  for (int cf = 0; cf < 6; ++cf) PS[w * 6 + cf][l] = acc2[cf];
  __syncthreads();
  for (int cf = w; cf < 6; cf += 4) {
    v4f sv = PS[cf][l] + PS[6 + cf][l] + PS[12 + cf][l] + PS[18 + cf][l];
    int c = cf * 16 + l15;
    int rb = r0 + lg * 4;
#pragma unroll
    for (int i = 0; i < 4; ++i) {
      int n = rb + i;
      float v = sv[i];
      if (c < 64) {
        unsigned short b = f2bf(v);
        RESF[(long long)n * 1536 + h * 64 + c] = b;
        ATOMF[(long long)n * 1280 + h * 64 + c] = b;
      } else if (c < 88) {
        OPTRAW[(long long)n * 288 + h * 24 + (c - 64)] = v;
      }
    }
  }
}

// ================= mega3: attn_pair (768) || finalize (768) =================
__global__ __launch_bounds__(256) void mega3(
    float* wsf, const float* __restrict__ rot, const float* __restrict__ trans,
    const float* __restrict__ tfno_wv, float* __restrict__ out)
{
  const int t = threadIdx.x;
  unsigned short* RESF  = (unsigned short*)(wsf + OFF_RESF);
  unsigned short* ATOMF = (unsigned short*)(wsf + OFF_ATOMF);
  if (blockIdx.x < 768) {
    __shared__ __align__(16) v4f PS[8][64];
    const unsigned short* Abf = (const unsigned short*)(wsf + OFF_ABF);
    const unsigned short* PZT = (const unsigned short*)(wsf + OFF_PZT);
    const int w = t >> 6, l = t & 63, l15 = l & 15, lg = l >> 4;
    const int n = blockIdx.x;
    const int hh = (l15 < 12) ? l15 : 0;
    const unsigned short* arow = Abf + ((long long)hh * 768 + n) * 768 + lg * 8;
    const unsigned short* pz = PZT + (long long)n * 32 * 768 + lg * 8;
    v4f acc[2] = {};
    for (int k0 = w * 192; k0 < w * 192 + 192; k0 += 32) {
      v8bf av = *(const v8bf*)(arow + k0);
#pragma unroll
      for (int cf = 0; cf < 2; ++cf) {
        v8bf bv = *(const v8bf*)(pz + (long long)(cf * 16 + l15) * 768 + k0);
        acc[cf] = __builtin_amdgcn_mfma_f32_16x16x32_bf16(av, bv, acc[cf], 0, 0, 0);
      }
    }
    PS[w * 2 + 0][l] = acc[0];
    PS[w * 2 + 1][l] = acc[1];
    __syncthreads();
    if (t < 128) {
      int cf = t >> 6, ll = t & 63;
      v4f sv = PS[cf][ll] + PS[2 + cf][ll] + PS[4 + cf][ll] + PS[6 + cf][ll];
      int zc = cf * 16 + (ll & 15);
#pragma unroll
      for (int i = 0; i < 4; ++i) {
        int hd = (ll >> 4) * 4 + i;
        if (hd < 12) {
          unsigned short b = f2bf(sv[i]);
          RESF[(long long)n * 1536 + 1152 + hd * 32 + zc] = b;
          ATOMF[(long long)n * 1280 + 864 + hd * 32 + zc] = b;
        }
      }
    }
    return;
  }
  // ---- finalize ----
  {
    const int n = blockIdx.x - 768;
    const float* OPTRAW = wsf + OFF_OPTRAW;
    const int* ISA = (const int*)wsf;
    const bool isa = ISA[n] != 0;
    __shared__ float R[9], T[3], opt2[96][3], norml[96];
    if (t < 9) R[t] = rot[(size_t)n * 9 + t];
    if (t < 3) T[t] = trans[(size_t)n * 3 + t];
    __syncthreads();
    for (int idx = t; idx < 288; idx += 256) {
      int hp = idx / 3, i = idx % 3;
      float x = OPTRAW[(size_t)n * 288 + hp * 3 + 0] - T[0];
      float y = OPTRAW[(size_t)n * 288 + hp * 3 + 1] - T[1];
      float z = OPTRAW[(size_t)n * 288 + hp * 3 + 2] - T[2];
      opt2[hp][i] = R[0 + i] * x + R[3 + i] * y + R[6 + i] * z;  // rot^T
    }
    __syncthreads();
    if (t < 96)
      norml[t] = sqrtf(opt2[t][0] * opt2[t][0] + opt2[t][1] * opt2[t][1] +
                       opt2[t][2] * opt2[t][2] + 1e-8f);
    __syncthreads();
    const long long rb = (long long)n * 1536;
    const long long ab = (long long)n * 1280;
    for (int idx = t; idx < 288; idx += 256) {
      int x = idx / 96, hp = idx % 96;
      RESF[rb + 768 + idx] = f2bf(opt2[hp][x]);
    }
    for (int idx = t; idx < 96; idx += 256) {
      unsigned short b = f2bf(norml[idx]);
      RESF[rb + 1056 + idx] = b;
      ATOMF[ab + 768 + idx] = b;
    }
    if (isa) {
      for (int idx = t; idx < 192; idx += 256) {
        int o = idx / 3, x = idx % 3;
        float a = 0.f;
        for (int p = 0; p < 96; ++p) a += opt2[p][x] * tfno_wv[p * 64 + o];
        out[(size_t)n * 384 + 192 + idx] = a;
      }
    }
  }
}

// ================= out GEMMs (predicated writes into d_out) =================
__global__ __launch_bounds__(256) void outg(float* wsf, const float* __restrict__ bout,
                                            float* __restrict__ out) {
  __shared__ __align__(16) char lds[16384];
  const int g = blockIdx.x;
  const int bt = g / 9, xt = g % 9;
  const int* ISA = (const int*)wsf;
  if (xt < 6)
    gemm16(lds, (const unsigned short*)(wsf + OFF_RESF), 1536,
           (const unsigned short*)(wsf + OFF_WOUTT), 1536, 384, bout, 2,
           nullptr, nullptr, 0, 384, xt * 64, bt * 16, ISA, out);
  else
    gemm16(lds, (const unsigned short*)(wsf + OFF_ATOMF), 1280,
           (const unsigned short*)(wsf + OFF_TFNOT), 1280, 320, nullptr, 3,
           nullptr, nullptr, 0, 192, (xt - 6) * 64, bt * 16, ISA, out);
}

extern "C" void kernel_launch(void* const* d_in, const int* in_sizes, int n_in,
                              void* d_out, int out_size, void* d_ws, size_t ws_size,
                              hipStream_t stream) {
  (void)in_sizes; (void)n_in; (void)out_size; (void)ws_size;
  const float* s      = (const float*)d_in[0];
  const float* z      = (const float*)d_in[1];
  const float* rot    = (const float*)d_in[2];
  const float* trans  = (const float*)d_in[3];
  const float* mask   = (const float*)d_in[4];
  const float* wq     = (const float*)d_in[6];
  const float* bq     = (const float*)d_in[7];
  const float* wkv    = (const float*)d_in[8];
  const float* bkv    = (const float*)d_in[9];
  const float* wqp    = (const float*)d_in[10];
  const float* bqp    = (const float*)d_in[11];
  const float* wkvp   = (const float*)d_in[12];
  const float* bkvp   = (const float*)d_in[13];
  const float* wb     = (const float*)d_in[14];
  const float* bb     = (const float*)d_in[15];
  const float* wdz    = (const float*)d_in[16];
  const float* bdz    = (const float*)d_in[17];
  const float* head_w = (const float*)d_in[18];
  const float* wout   = (const float*)d_in[19];
  const float* bout   = (const float*)d_in[20];
  const float* tfnq_ws  = (const float*)d_in[21];
  const float* tfnq_wv  = (const float*)d_in[22];
  const float* tfnkv_ws = (const float*)d_in[23];
  const float* tfnkv_wv = (const float*)d_in[24];
  const float* tfno_ws  = (const float*)d_in[25];
  const float* tfno_wv  = (const float*)d_in[26];

  float* wsf = (float*)d_ws;

  prep0<<<2797, 256, 0, stream>>>(wsf, s, wq, wkv, wqp, wkvp, tfnq_ws, tfnkv_ws,
                                  wout, tfno_ws, wb, wdz, bb, bdz,
                                  (const unsigned int*)d_in[5]);
  mega1<<<8544, 256, 0, stream>>>(wsf, z, bq, bkv, bqp, bkvp);
  prep_qkv<<<768, 256, 0, stream>>>(wsf, s, rot, trans, head_w, tfnq_wv, tfnkv_wv);
  mega2<<<576, 256, 0, stream>>>(wsf, mask);
  mega3<<<1536, 256, 0, stream>>>(wsf, rot, trans, tfno_wv, (float*)d_out);
  outg<<<432, 256, 0, stream>>>(wsf, bout, (float*)d_out);
}